// Round 1
// baseline (2110.064 us; speedup 1.0000x reference)
//
#include <hip/hip_runtime.h>
#include <stdint.h>

// CouncilLayer: out[n,c] = sum_e softmax(x@gw+gb)[n,e] * (gelu(x@w1[e]+b1[e]) @ w2[e] + b2[e])[c]
// N=2048 tokens, C=768, E=32, H=3072. All fp32 in global; compute in bf16 MFMA.
//
// Pipeline:
//   cvt_x:      x fp32 -> xb bf16
//   gate_k:     gates[n,e] = softmax(x@gw+gb)
//   bias_out:   out[n,c]  = sum_e gates[n,e]*b2[e,c]   (full overwrite of d_out)
//   per expert-group g (G experts):
//     pack_b(w1g) -> w1b   (bf16, LDS-image tiles [n(128)][k(32)], 8KB/tile)
//     gemm<1>: h'[n, eH+h] = bf16( gates[n,e] * gelu(x@w1 + b1) )
//     pack_b(w2g) -> w2b
//     gemm<2>: out += h' @ w2   (split-K, atomicAdd fp32)

typedef unsigned short u16;
typedef __attribute__((ext_vector_type(8))) short short8;     // bf16 MFMA A/B frag (4 VGPR)
typedef __attribute__((ext_vector_type(8))) unsigned short ushort8v;
typedef __attribute__((ext_vector_type(4))) unsigned short ushort4v;
typedef __attribute__((ext_vector_type(4))) float float4v;    // MFMA C/D frag

#define DEV __device__ __forceinline__

DEV u16 rne_bf16(float f) {
  union { float f; uint32_t u; } v; v.f = f;
  uint32_t u = v.u;
  u += 0x7FFFu + ((u >> 16) & 1u);   // round-to-nearest-even
  return (u16)(u >> 16);
}

// async global->LDS, 16B per lane. LDS dst is wave-uniform base; lanes scatter at +lane*16.
DEV void load_lds16(const void* g, void* l) {
  __builtin_amdgcn_global_load_lds(
      (const __attribute__((address_space(1))) unsigned int*)g,
      (__attribute__((address_space(3))) unsigned int*)l,
      16, 0, 0);
}

// ---------------- small kernels ----------------

__global__ void cvt_x_kernel(const float* __restrict__ x, u16* __restrict__ xb, int n4) {
  int i = blockIdx.x * 256 + threadIdx.x;
  if (i >= n4) return;
  float4v v = *(const float4v*)(x + (size_t)i * 4);
  ushort4v o;
  o[0] = rne_bf16(v[0]); o[1] = rne_bf16(v[1]);
  o[2] = rne_bf16(v[2]); o[3] = rne_bf16(v[3]);
  *(ushort4v*)(xb + (size_t)i * 4) = o;
}

// one wave per block; half-waves each do one token. lanes 0..31 = experts.
__global__ void gate_kernel(const float* __restrict__ x, const float* __restrict__ gw,
                            const float* __restrict__ gb, float* __restrict__ gates) {
  int lane = threadIdx.x;
  int tok = blockIdx.x * 2 + (lane >> 5);
  int e = lane & 31;
  const float* xr = x + (size_t)tok * 768;
  float s = gb[e];
  #pragma unroll 4
  for (int c = 0; c < 768; ++c) s += xr[c] * gw[c * 32 + e];
  float mx = s;
  #pragma unroll
  for (int o = 16; o >= 1; o >>= 1) mx = fmaxf(mx, __shfl_xor(mx, o, 32));
  float ex = __expf(s - mx);
  float sum = ex;
  #pragma unroll
  for (int o = 16; o >= 1; o >>= 1) sum += __shfl_xor(sum, o, 32);
  gates[tok * 32 + e] = ex / sum;
}

// out[n,c] = sum_e gates[n,e] * b2[e,c]   (handles b2 generally; also inits d_out)
__global__ void bias_out_kernel(const float* __restrict__ gates, const float* __restrict__ b2,
                                float* __restrict__ out) {
  int idx = blockIdx.x * 256 + threadIdx.x;   // < 2048*768
  int n = idx / 768, c = idx - n * 768;
  const float* g = gates + n * 32;
  float s = 0.f;
  #pragma unroll
  for (int e = 0; e < 32; ++e) s += g[e] * b2[e * 768 + c];
  out[idx] = s;
}

// pack fp32 [K x N] (possibly expert-strided cols) into bf16 tiles [nt][kt][n(128)][k(32)].
// tile inner layout == GEMM LDS B image: row n (32 k, 64B) contiguous.
__global__ void pack_b_kernel(const float* __restrict__ in, u16* __restrict__ out,
                              int ktiles, int n_per_e, long e_stride, int row_stride) {
  int kt = blockIdx.x, nt = blockIdx.y;
  int n0 = nt * 128;
  int e = n0 / n_per_e;
  int nl = n0 - e * n_per_e;
  const float* src = in + (long)e * e_stride + (long)kt * 32 * row_stride + nl;

  __shared__ u16 lds[32 * 136];
  int t = threadIdx.x;
  {
    int k = t >> 3, nq = (t & 7) * 16;
    const float* p = src + (long)k * row_stride + nq;
    u16 tmp[16];
    #pragma unroll
    for (int i = 0; i < 16; i += 4) {
      float4v v = *(const float4v*)(p + i);
      tmp[i] = rne_bf16(v[0]); tmp[i + 1] = rne_bf16(v[1]);
      tmp[i + 2] = rne_bf16(v[2]); tmp[i + 3] = rne_bf16(v[3]);
    }
    *(ushort8v*)&lds[k * 136 + nq]     = *(ushort8v*)&tmp[0];
    *(ushort8v*)&lds[k * 136 + nq + 8] = *(ushort8v*)&tmp[8];
  }
  __syncthreads();
  {
    int n = t >> 1, half = t & 1;
    u16 v[16];
    #pragma unroll
    for (int j = 0; j < 16; ++j) v[j] = lds[(half * 16 + j) * 136 + n];
    u16* tile = out + ((long)nt * ktiles + kt) * 4096;
    *(ushort8v*)(tile + n * 32 + half * 16)     = *(ushort8v*)&v[0];
    *(ushort8v*)(tile + n * 32 + half * 16 + 8) = *(ushort8v*)&v[8];
  }
}

// ---------------- GEMM ----------------
// C[128x128] per block, 4 waves in 2x2, each wave 64x64 via 4x4 mfma_f32_16x16x32_bf16.
// A: bf16 row-major [M x Ktot], lda elements.  B: packed tiles (see pack_b_kernel).
// MODE 1: out = bf16( gates[m,e]*gelu(acc + b1) ) into h' (ldo = group K width)
// MODE 2: atomicAdd fp32 into out (ldo = 768)
template <int MODE>
__global__ __launch_bounds__(256) void gemm_tile(
    const u16* __restrict__ A, long lda,
    const u16* __restrict__ Bp, int ktiles_total, int nkt,
    void* __restrict__ outp, long ldo,
    const float* __restrict__ gates, const float* __restrict__ b1, int e_base) {

  __shared__ u16 As[128 * 32];
  __shared__ u16 Bs[128 * 32];
  __shared__ float gbuf[128];

  const int tid = threadIdx.x;
  const int wave = tid >> 6;
  const int lane = tid & 63;
  const int wr = wave >> 1, wc = wave & 1;
  const int m0 = blockIdx.x * 128;
  const int n0 = blockIdx.y * 128;
  const int kt_begin = blockIdx.z * nkt;

  float4v acc[4][4] = {};

  // staging addresses
  const int arow = wave * 32 + (lane >> 2);                 // + j*16
  const u16* gA = A + (long)(m0 + arow) * lda + (long)kt_begin * 32 + (lane & 3) * 8;
  const u16* gB = Bp + ((long)blockIdx.y * ktiles_total + kt_begin) * 4096
                     + (wave * 2) * 512 + lane * 8;
  u16* ldsA0 = &As[(wave * 32) * 32];
  u16* ldsB0 = &Bs[(wave * 2) * 512];

  const int fa = (lane & 15) * 32 + (lane >> 4) * 8;        // frag base (row (lane&15))

  for (int kt = 0; kt < nkt; ++kt) {
    __syncthreads();
    load_lds16(gA,            ldsA0);
    load_lds16(gA + 16 * lda, ldsA0 + 16 * 32);
    load_lds16(gB,            ldsB0);
    load_lds16(gB + 512,      ldsB0 + 512);
    gA += 32; gB += 4096;
    __syncthreads();

    short8 af[4], bf[4];
    #pragma unroll
    for (int i = 0; i < 4; ++i)
      af[i] = *(const short8*)&As[(wr * 64 + i * 16) * 32 + fa];
    #pragma unroll
    for (int i = 0; i < 4; ++i)
      bf[i] = *(const short8*)&Bs[(wc * 64 + i * 16) * 32 + fa];
    #pragma unroll
    for (int mi = 0; mi < 4; ++mi)
      #pragma unroll
      for (int ni = 0; ni < 4; ++ni)
        acc[mi][ni] = __builtin_amdgcn_mfma_f32_16x16x32_bf16(af[mi], bf[ni], acc[mi][ni], 0, 0, 0);
  }

  if (MODE == 1) {
    int e_loc = n0 / 3072;
    int h0 = n0 - e_loc * 3072;
    int eg = e_base + e_loc;
    if (tid < 128) gbuf[tid] = gates[(m0 + tid) * 32 + eg];
    __syncthreads();
    u16* out = (u16*)outp;
    const float* b1e = b1 + (long)eg * 3072 + h0;
    #pragma unroll
    for (int ni = 0; ni < 4; ++ni) {
      int ncol = wc * 64 + ni * 16 + (lane & 15);
      float bv = b1e[ncol];
      #pragma unroll
      for (int mi = 0; mi < 4; ++mi) {
        #pragma unroll
        for (int r = 0; r < 4; ++r) {
          int mrow = wr * 64 + mi * 16 + (lane >> 4) * 4 + r;
          float v = acc[mi][ni][r] + bv;
          v = 0.5f * v * (1.0f + erff(v * 0.70710678118654752440f));  // exact gelu
          v *= gbuf[mrow];
          out[(long)(m0 + mrow) * ldo + (n0 + ncol)] = rne_bf16(v);
        }
      }
    }
  } else {
    float* out = (float*)outp;
    #pragma unroll
    for (int ni = 0; ni < 4; ++ni) {
      int ncol = n0 + wc * 64 + ni * 16 + (lane & 15);
      #pragma unroll
      for (int mi = 0; mi < 4; ++mi) {
        #pragma unroll
        for (int r = 0; r < 4; ++r) {
          int mrow = m0 + wr * 64 + mi * 16 + (lane >> 4) * 4 + r;
          atomicAdd(&out[(long)mrow * ldo + ncol], acc[mi][ni][r]);
        }
      }
    }
  }
}

// ---------------- launch ----------------

extern "C" void kernel_launch(void* const* d_in, const int* in_sizes, int n_in,
                              void* d_out, int out_size, void* d_ws, size_t ws_size,
                              hipStream_t stream) {
  (void)in_sizes; (void)n_in; (void)out_size;
  const float* x  = (const float*)d_in[0];
  const float* gw = (const float*)d_in[1];
  const float* gb = (const float*)d_in[2];
  const float* w1 = (const float*)d_in[3];
  const float* b1 = (const float*)d_in[4];
  const float* w2 = (const float*)d_in[5];
  const float* b2 = (const float*)d_in[6];
  float* out = (float*)d_out;

  const long N = 2048, C = 768, H = 3072;

  // expert-group size G: ws need = 3,407,872 + G*22,020,096 bytes
  int G = 32;
  while (G > 1 && (size_t)(3407872L + (long)G * 22020096L) > ws_size) G >>= 1;

  char* p = (char*)d_ws;
  u16*   xb    = (u16*)p;   p += N * C * 2;
  float* gates = (float*)p; p += N * 32 * 4;
  u16*   w1b   = (u16*)p;   p += (long)G * C * H * 2;
  u16*   w2b   = (u16*)p;   p += (long)G * H * C * 2;
  u16*   hbuf  = (u16*)p;

  cvt_x_kernel<<<(N * C / 4 + 255) / 256, 256, 0, stream>>>(x, xb, (int)(N * C / 4));
  gate_kernel<<<N / 2, 64, 0, stream>>>(x, gw, gb, gates);
  bias_out_kernel<<<N * C / 256, 256, 0, stream>>>(gates, b2, out);

  const int ngroups = 32 / G;
  for (int g = 0; g < ngroups; ++g) {
    const float* w1g = w1 + (long)g * G * C * H;
    const float* w2g = w2 + (long)g * G * H * C;

    // pack w1 group: K=768 (24 kt), N=G*H (24G nt); cols expert-strided
    dim3 pg1(24, 24 * G);
    pack_b_kernel<<<pg1, 256, 0, stream>>>(w1g, w1b, 24, (int)H, (long)C * H, (int)H);

    // gemm1: h' = gate*gelu(x@w1+b1), bf16
    dim3 gg1(16, 24 * G, 1);
    gemm_tile<1><<<gg1, 256, 0, stream>>>(xb, C, w1b, 24, 24,
                                          (void*)hbuf, (long)G * H, gates, b1, g * G);

    // pack w2 group: K=G*H (96G kt), N=768 (6 nt); plain row-major
    dim3 pg2(96 * G, 6);
    pack_b_kernel<<<pg2, 256, 0, stream>>>(w2g, w2b, 96 * G, 768, 0L, 768);

    // gemm2: out += h' @ w2, split-K=8, atomic fp32
    dim3 gg2(16, 6, 8);
    gemm_tile<2><<<gg2, 256, 0, stream>>>(hbuf, (long)G * H, w2b, 96 * G, 12 * G,
                                          (void*)out, 768, nullptr, nullptr, 0);
  }
}

// Round 2
// 1699.391 us; speedup vs baseline: 1.2417x; 1.2417x over previous
//
#include <hip/hip_runtime.h>
#include <stdint.h>

// CouncilLayer: out[n,c] = sum_e softmax(x@gw+gb)[n,e] * (gelu(x@w1[e]+b1[e]) @ w2[e] + b2[e])[c]
// N=2048 tokens, C=768, E=32, H=3072. fp32 in/out; bf16 MFMA compute.
//
// R2: BK=64 K-loop (half the barrier drains), XOR-swizzled LDS images
// (conflict-free ds_read_b128), branchless fast erf (A&S 7.1.26, |err|<=1.5e-7),
// gemm2 split-K via partial buffers + reduce (no atomics).

typedef unsigned short u16;
typedef __attribute__((ext_vector_type(8))) short short8;     // bf16 MFMA A/B frag
typedef __attribute__((ext_vector_type(8))) unsigned short ushort8v;
typedef __attribute__((ext_vector_type(4))) unsigned short ushort4v;
typedef __attribute__((ext_vector_type(4))) float float4v;

#define DEV __device__ __forceinline__

DEV u16 rne_bf16(float f) {
  union { float f; uint32_t u; } v; v.f = f;
  uint32_t u = v.u;
  u += 0x7FFFu + ((u >> 16) & 1u);
  return (u16)(u >> 16);
}

// branchless erf, Abramowitz-Stegun 7.1.26, |err| <= 1.5e-7
DEV float fast_erf(float x) {
  float ax = __builtin_fabsf(x);
  float t = __builtin_amdgcn_rcpf(__builtin_fmaf(0.3275911f, ax, 1.0f));
  float p = t * (0.254829592f + t * (-0.284496736f + t * (1.421413741f +
            t * (-1.453152027f + t * 1.061405429f))));
  float r = 1.0f - p * __expf(-ax * ax);
  return __builtin_copysignf(r, x);
}

DEV void load_lds16(const void* g, void* l) {
  __builtin_amdgcn_global_load_lds(
      (const __attribute__((address_space(1))) unsigned int*)g,
      (__attribute__((address_space(3))) unsigned int*)l,
      16, 0, 0);
}

// ---------------- small kernels ----------------

__global__ void cvt_x_kernel(const float* __restrict__ x, u16* __restrict__ xb, int n4) {
  int i = blockIdx.x * 256 + threadIdx.x;
  if (i >= n4) return;
  float4v v = *(const float4v*)(x + (size_t)i * 4);
  ushort4v o;
  o[0] = rne_bf16(v[0]); o[1] = rne_bf16(v[1]);
  o[2] = rne_bf16(v[2]); o[3] = rne_bf16(v[3]);
  *(ushort4v*)(xb + (size_t)i * 4) = o;
}

__global__ void gate_kernel(const float* __restrict__ x, const float* __restrict__ gw,
                            const float* __restrict__ gb, float* __restrict__ gates) {
  int lane = threadIdx.x;
  int tok = blockIdx.x * 2 + (lane >> 5);
  int e = lane & 31;
  const float* xr = x + (size_t)tok * 768;
  float s = gb[e];
  #pragma unroll 4
  for (int c = 0; c < 768; ++c) s += xr[c] * gw[c * 32 + e];
  float mx = s;
  #pragma unroll
  for (int o = 16; o >= 1; o >>= 1) mx = fmaxf(mx, __shfl_xor(mx, o, 32));
  float ex = __expf(s - mx);
  float sum = ex;
  #pragma unroll
  for (int o = 16; o >= 1; o >>= 1) sum += __shfl_xor(sum, o, 32);
  gates[tok * 32 + e] = ex / sum;
}

__global__ void bias_out_kernel(const float* __restrict__ gates, const float* __restrict__ b2,
                                float* __restrict__ out) {
  int idx = blockIdx.x * 256 + threadIdx.x;
  int n = idx / 768;
  int c = idx - n * 768;
  const float* g = gates + n * 32;
  float s = 0.f;
  #pragma unroll
  for (int e = 0; e < 32; ++e) s += g[e] * b2[e * 768 + c];
  out[idx] = s;
}

// reduce split-K partials into out: out += sum_z partial[z]
__global__ void reduce_kernel(const float* __restrict__ part, float* __restrict__ out, int n4) {
  int i = blockIdx.x * 256 + threadIdx.x;
  if (i >= n4) return;
  float4v o = *(const float4v*)(out + (size_t)i * 4);
  #pragma unroll
  for (int z = 0; z < 8; ++z) {
    float4v p = *(const float4v*)(part + (size_t)z * (2048L * 768) + (size_t)i * 4);
    o[0] += p[0]; o[1] += p[1]; o[2] += p[2]; o[3] += p[3];
  }
  *(float4v*)(out + (size_t)i * 4) = o;
}

// pack fp32 [K x N] into bf16 tiles [nt][kt][n(128)][k(64)], 16KB/tile,
// with 16B-chunk XOR swizzle: chunk c of row n stored at slot c^(n&7).
__global__ void pack_b_kernel(const float* __restrict__ in, u16* __restrict__ out,
                              int ktiles, int n_per_e, long e_stride, int row_stride) {
  int kt = blockIdx.x, nt = blockIdx.y;
  int n0 = nt * 128;
  int e = n0 / n_per_e;
  int nl = n0 - e * n_per_e;
  const float* src = in + (long)e * e_stride + (long)kt * 64 * row_stride + nl;

  __shared__ u16 lds[64 * 136];
  int t = threadIdx.x;
  {
    int k = t >> 2, nq = (t & 3) * 32;
    const float* p = src + (long)k * row_stride + nq;
    u16 tmp[32];
    #pragma unroll
    for (int i = 0; i < 32; i += 4) {
      float4v v = *(const float4v*)(p + i);
      tmp[i] = rne_bf16(v[0]); tmp[i + 1] = rne_bf16(v[1]);
      tmp[i + 2] = rne_bf16(v[2]); tmp[i + 3] = rne_bf16(v[3]);
    }
    #pragma unroll
    for (int i = 0; i < 32; i += 8)
      *(ushort8v*)&lds[k * 136 + nq + i] = *(ushort8v*)&tmp[i];
  }
  __syncthreads();
  {
    int n = t >> 1, half = t & 1;
    u16 v[32];
    #pragma unroll
    for (int j = 0; j < 32; ++j) v[j] = lds[(half * 32 + j) * 136 + n];
    u16* tile = out + ((long)nt * ktiles + kt) * 8192 + n * 64;
    int sw = n & 7;
    #pragma unroll
    for (int cc = 0; cc < 4; ++cc) {
      int c = half * 4 + cc;
      *(ushort8v*)(tile + ((c ^ sw) * 8)) = *(ushort8v*)&v[cc * 8];
    }
  }
}

// ---------------- GEMM ----------------
// C[128x128] per block, 4 waves 2x2, each 64x64 via 4x4 mfma_f32_16x16x32_bf16, BK=64.
// A: bf16 row-major [M x Ktot] (lane-swizzled staging). B: packed swizzled tiles.
// MODE 1: out = bf16(gates[m,e]*gelu(acc+b1)) -> h'   MODE 2: fp32 partial store.
template <int MODE>
__global__ __launch_bounds__(256) void gemm_tile(
    const u16* __restrict__ A, long lda,
    const u16* __restrict__ Bp, int ktiles_total, int nkt,
    void* __restrict__ outp, long ldo,
    const float* __restrict__ gates, const float* __restrict__ b1, int e_base) {

  __shared__ u16 As[128 * 64];
  __shared__ u16 Bs[128 * 64];
  __shared__ float gbuf[128];

  const int tid = threadIdx.x;
  const int wave = tid >> 6;
  const int lane = tid & 63;
  const int wr = wave >> 1, wc = wave & 1;
  const int m0 = blockIdx.x * 128;
  const int n0 = blockIdx.y * 128;
  const int kt_begin = blockIdx.z * nkt;

  float4v acc[4][4] = {};

  // A staging: lane l fetches row (l>>3), global chunk (l&7)^(l>>3); LDS slot l&7.
  const int lr = lane >> 3, l8 = lane & 7;
  const u16* gA = A + (long)(m0 + wave * 32 + lr) * lda + (long)kt_begin * 64
                    + (long)(l8 ^ lr) * 8;
  const u16* gB = Bp + ((long)blockIdx.y * ktiles_total + kt_begin) * 8192
                     + wave * 2048 + lane * 8;
  u16* ldsA0 = &As[wave * 2048];
  u16* ldsB0 = &Bs[wave * 2048];

  // fragment read params: row = base+(lane&15); elem = row*64 + ((s*4+q)^(lane&7))*8
  const int frow = lane & 15;
  const int fq = lane >> 4;
  const int fxor = lane & 7;

  for (int kt = 0; kt < nkt; ++kt) {
    __syncthreads();
    #pragma unroll
    for (int j = 0; j < 4; ++j) {
      load_lds16(gA + (long)j * 8 * lda, ldsA0 + j * 512);
      load_lds16(gB + j * 512,           ldsB0 + j * 512);
    }
    gA += 64; gB += 8192;
    __syncthreads();

    #pragma unroll
    for (int s = 0; s < 2; ++s) {
      const int co = ((s * 4 + fq) ^ fxor) * 8;
      short8 af[4], bf[4];
      #pragma unroll
      for (int i = 0; i < 4; ++i)
        af[i] = *(const short8*)&As[(wr * 64 + i * 16 + frow) * 64 + co];
      #pragma unroll
      for (int i = 0; i < 4; ++i)
        bf[i] = *(const short8*)&Bs[(wc * 64 + i * 16 + frow) * 64 + co];
      #pragma unroll
      for (int mi = 0; mi < 4; ++mi)
        #pragma unroll
        for (int ni = 0; ni < 4; ++ni)
          acc[mi][ni] = __builtin_amdgcn_mfma_f32_16x16x32_bf16(af[mi], bf[ni], acc[mi][ni], 0, 0, 0);
    }
  }

  if (MODE == 1) {
    int e_loc = n0 / 3072;
    int h0 = n0 - e_loc * 3072;
    int eg = e_base + e_loc;
    if (tid < 128) gbuf[tid] = gates[(m0 + tid) * 32 + eg];
    __syncthreads();
    u16* out = (u16*)outp;
    const float* b1e = b1 + (long)eg * 3072 + h0;
    #pragma unroll
    for (int ni = 0; ni < 4; ++ni) {
      int ncol = wc * 64 + ni * 16 + frow;
      float bv = b1e[ncol];
      #pragma unroll
      for (int mi = 0; mi < 4; ++mi) {
        #pragma unroll
        for (int r = 0; r < 4; ++r) {
          int mrow = wr * 64 + mi * 16 + fq * 4 + r;
          float v = acc[mi][ni][r] + bv;
          v = 0.5f * v * (1.0f + fast_erf(v * 0.70710678118654752440f));
          v *= gbuf[mrow];
          out[(long)(m0 + mrow) * ldo + (n0 + ncol)] = rne_bf16(v);
        }
      }
    }
  } else {
    float* out = (float*)outp + (long)blockIdx.z * (2048L * 768);
    #pragma unroll
    for (int ni = 0; ni < 4; ++ni) {
      int ncol = n0 + wc * 64 + ni * 16 + frow;
      #pragma unroll
      for (int mi = 0; mi < 4; ++mi) {
        #pragma unroll
        for (int r = 0; r < 4; ++r) {
          int mrow = m0 + wr * 64 + mi * 16 + fq * 4 + r;
          out[(long)mrow * ldo + ncol] = acc[mi][ni][r];
        }
      }
    }
  }
}

// ---------------- launch ----------------

extern "C" void kernel_launch(void* const* d_in, const int* in_sizes, int n_in,
                              void* d_out, int out_size, void* d_ws, size_t ws_size,
                              hipStream_t stream) {
  (void)in_sizes; (void)n_in; (void)out_size;
  const float* x  = (const float*)d_in[0];
  const float* gw = (const float*)d_in[1];
  const float* gb = (const float*)d_in[2];
  const float* w1 = (const float*)d_in[3];
  const float* b1 = (const float*)d_in[4];
  const float* w2 = (const float*)d_in[5];
  const float* b2 = (const float*)d_in[6];
  float* out = (float*)d_out;

  const long N = 2048, C = 768, H = 3072;

  // ws: xb 3.1MB + gates 0.26MB + partials 50.3MB + G*(w1b 4.7 + w2b 4.7 + hbuf 12.6)MB
  const long base_need = N * C * 2 + N * 32 * 4 + 8L * N * C * 4;
  int G = 32;
  while (G > 1 && (size_t)(base_need + (long)G * (C * H * 2 * 2 + N * H * 2)) > ws_size) G >>= 1;

  char* p = (char*)d_ws;
  u16*   xb    = (u16*)p;   p += N * C * 2;
  float* gates = (float*)p; p += N * 32 * 4;
  float* parts = (float*)p; p += 8L * N * C * 4;
  u16*   w1b   = (u16*)p;   p += (long)G * C * H * 2;
  u16*   w2b   = (u16*)p;   p += (long)G * H * C * 2;
  u16*   hbuf  = (u16*)p;

  cvt_x_kernel<<<(N * C / 4 + 255) / 256, 256, 0, stream>>>(x, xb, (int)(N * C / 4));
  gate_kernel<<<N / 2, 64, 0, stream>>>(x, gw, gb, gates);
  bias_out_kernel<<<N * C / 256, 256, 0, stream>>>(gates, b2, out);

  const int ngroups = 32 / G;
  for (int g = 0; g < ngroups; ++g) {
    const float* w1g = w1 + (long)g * G * C * H;
    const float* w2g = w2 + (long)g * G * H * C;

    // pack w1 group: K=768 -> 12 ktiles, N=G*H -> 24G ntiles (expert-strided cols)
    dim3 pg1(12, 24 * G);
    pack_b_kernel<<<pg1, 256, 0, stream>>>(w1g, w1b, 12, (int)H, (long)C * H, (int)H);

    // gemm1: h' = gate*gelu(x@w1+b1), bf16. K=768 -> nkt=12
    dim3 gg1(16, 24 * G, 1);
    gemm_tile<1><<<gg1, 256, 0, stream>>>(xb, C, w1b, 12, 12,
                                          (void*)hbuf, (long)G * H, gates, b1, g * G);

    // pack w2 group: K=G*H -> 48G ktiles, N=768 -> 6 ntiles
    dim3 pg2(48 * G, 6);
    pack_b_kernel<<<pg2, 256, 0, stream>>>(w2g, w2b, 48 * G, 768, 0L, 768);

    // gemm2: partials[z] = h' @ w2 slice. ktiles=48G, split-K 8 -> nkt=6G
    dim3 gg2(16, 6, 8);
    gemm_tile<2><<<gg2, 256, 0, stream>>>(hbuf, (long)G * H, w2b, 48 * G, 6 * G,
                                          (void*)parts, 768, nullptr, nullptr, 0);

    reduce_kernel<<<(int)((N * C / 4 + 255) / 256), 256, 0, stream>>>(parts, out, (int)(N * C / 4));
  }
}